// Round 6
// baseline (128.106 us; speedup 1.0000x reference)
//
#include <hip/hip_runtime.h>
#include <hip/hip_bf16.h>

#define B_ROWS 8192
#define C_IN   4096
#define G_GRP  8
#define CG     512
#define J_RANK 512
#define GBK    32
#define GNKB   (CG / GBK)   // 16 K-steps

#define RPB    8                      // rows per permute block
#define PERM_BLOCKS (B_ROWS / RPB)    // 1024

typedef __attribute__((ext_vector_type(8))) short bf16x8;
typedef __attribute__((ext_vector_type(4))) float f32x4;
typedef __attribute__((ext_vector_type(8))) unsigned short u16x8;

struct ushort4v { unsigned short x, y, z, w; };

__device__ __forceinline__ unsigned short f2bf(float f) {
    unsigned int u = __float_as_uint(f);
    unsigned int r = (u + 0x7FFFu + ((u >> 16) & 1u)) >> 16;  // RNE
    return (unsigned short)r;
}

// ---------------- kernel 1: convert weights fp32 -> bf16 ----------------
__global__ __launch_bounds__(256) void convert_w_kernel(
    const float* __restrict__ w, unsigned short* __restrict__ wb, int n4) {
    int i = blockIdx.x * 256 + threadIdx.x;
    if (i >= n4) return;
    float4 v = ((const float4*)w)[i];
    ushort4v o;
    o.x = f2bf(v.x); o.y = f2bf(v.y); o.z = f2bf(v.z); o.w = f2bf(v.w);
    ((ushort4v*)wb)[i] = o;
}

// -------- kernel 2: gather-permute x, depth-3 LDS pipeline --------------
// 1024 blocks x 8 rows, 48KB LDS -> 3 blocks/CU co-resident (TLP).
// Gather via LDS (global scatter is TA-throughput-bound, R4 evidence).
// Counted vmcnt ladder (loads 4/row, stores 2/row, in-order retirement):
//   r0:8  r1:10  steady:12  r=RPB-2:8  r=RPB-1:4
__global__ __launch_bounds__(256) void permute_x_kernel(
    const float* __restrict__ x, const int* __restrict__ arr,
    unsigned short* __restrict__ xp) {
    __shared__ float buf[3][C_IN];   // 48 KB
    const int tid  = threadIdx.x;
    const int row0 = blockIdx.x * RPB;

    // arrangements declared int64 in the reference; harness may hand int32.
    // int64 little-endian => odd int32 words all 0 (values < 4096).
    const bool is64 = (arr[1] == 0 && arr[3] == 0 && arr[5] == 0 && arr[7] == 0);

    int sidx[16];
#pragma unroll
    for (int pass = 0; pass < 2; ++pass)
#pragma unroll
        for (int k = 0; k < 8; ++k) {
            int p = pass * 2048 + tid * 8 + k;
            sidx[pass * 8 + k] = is64 ? arr[2 * p] : arr[p];
        }

#define PSTAGE(bufi, r)                                                      \
    do {                                                                     \
        const float* src_ = x + (size_t)(row0 + (r)) * C_IN;                 \
        _Pragma("unroll")                                                    \
        for (int i_ = 0; i_ < 4; ++i_) {                                     \
            int c_ = i_ * 256 + tid;                                         \
            __builtin_amdgcn_global_load_lds(                                \
                (const __attribute__((address_space(1))) unsigned int*)      \
                    (src_ + c_ * 4),                                         \
                (__attribute__((address_space(3))) unsigned int*)            \
                    (&buf[bufi][0] + c_ * 4),                                \
                16, 0, 0);                                                   \
        }                                                                    \
    } while (0)

    PSTAGE(0, 0);
    PSTAGE(1, 1);
    PSTAGE(2, 2);

#pragma unroll
    for (int r = 0; r < RPB; ++r) {
        if (r == 0)            asm volatile("s_waitcnt vmcnt(8)"  ::: "memory");
        else if (r == 1)       asm volatile("s_waitcnt vmcnt(10)" ::: "memory");
        else if (r == RPB - 2) asm volatile("s_waitcnt vmcnt(8)"  ::: "memory");
        else if (r == RPB - 1) asm volatile("s_waitcnt vmcnt(4)"  ::: "memory");
        else                   asm volatile("s_waitcnt vmcnt(12)" ::: "memory");
        __builtin_amdgcn_s_barrier();          // whole block's row r in LDS
        __builtin_amdgcn_sched_barrier(0);

        const int bi = r % 3;                  // compile-time (unrolled)
        unsigned short* orow = xp + (size_t)(row0 + r) * C_IN;
#pragma unroll
        for (int pass = 0; pass < 2; ++pass) {
            u16x8 o;
#pragma unroll
            for (int k = 0; k < 8; ++k)
                o[k] = f2bf(buf[bi][sidx[pass * 8 + k]]);
            *(u16x8*)(orow + pass * 2048 + tid * 8) = o;
        }

        __builtin_amdgcn_sched_barrier(0);
        __builtin_amdgcn_s_barrier();          // all waves done reading buf[bi]
        if (r + 3 < RPB) PSTAGE(bi, r + 3);    // slot (r+3)%3 == bi, now safe
    }
#undef PSTAGE
}

// ---------------- kernel 3: grouped GEMM (bf16 MFMA) ---------------------
// 128x512 tile, 8 waves arranged 1x8: WAVE TILE = 128x64 (tall).
// Per K-step/wave: 12 ds_read_b128 feed 64 MFMA (192 B/MFMA, was 384) --
// halves the LDS-read demand per FLOP (R5's inner loop was LDS-BW-bound).
// A (xp) read once. g = blockIdx&7 pins group to XCD (B-panel L2-resident).
// Counted vmcnt(5): next tile's 5 loads stay in flight across the barrier.
__global__ __launch_bounds__(512, 2) void gemm_kernel(
    const unsigned short* __restrict__ Xp,   // [B][4096] bf16 (permuted)
    const unsigned short* __restrict__ Wb,   // [G][J][CG] bf16
    const float* __restrict__ bias,          // [G][J]
    float* __restrict__ out) {               // [B][4096] fp32
    __shared__ unsigned short ldsA[2][128 * GBK];   // 2 x 8 KB
    __shared__ unsigned short ldsB[2][512 * GBK];   // 2 x 32 KB

    const int tid = threadIdx.x;
    const int g   = blockIdx.x & 7;    // group -> XCD (round-robin dispatch)
    const int mt  = blockIdx.x >> 3;   // 64 m-tiles

    const int l  = tid & 63;
    const int wv = tid >> 6;           // wave 0..7: cols wv*64..+64, all 128 rows
    const int lr = l & 15;
    const int lk = (l >> 4) << 3;      // k-slice 0,8,16,24

    const unsigned short* Abase = Xp + (size_t)(mt * 128) * C_IN + g * CG;
    const unsigned short* Bbase = Wb + (size_t)g * J_RANK * CG;

    f32x4 acc[8][4];
#pragma unroll
    for (int m = 0; m < 8; ++m)
#pragma unroll
        for (int n = 0; n < 4; ++n) acc[m][n] = (f32x4){0.f, 0.f, 0.f, 0.f};

#define GSTAGE(slot, kb)                                                         \
    do {                                                                         \
        /* A: 128x32 = 512 x 16B chunks, 1/thread */                             \
        {                                                                        \
            int c = tid;                                                         \
            __builtin_amdgcn_global_load_lds(                                    \
                (const __attribute__((address_space(1))) unsigned int*)          \
                    (Abase + (size_t)(c >> 2) * C_IN + (kb) * GBK + (c & 3) * 8),\
                (__attribute__((address_space(3))) unsigned int*)                \
                    (&ldsA[slot][0] + c * 8),                                    \
                16, 0, 0);                                                       \
        }                                                                        \
        /* B: 512x32 = 2048 x 16B chunks, 4/thread */                            \
        _Pragma("unroll")                                                        \
        for (int i = 0; i < 4; ++i) {                                            \
            int cb = i * 512 + tid;                                              \
            __builtin_amdgcn_global_load_lds(                                    \
                (const __attribute__((address_space(1))) unsigned int*)          \
                    (Bbase + (size_t)(cb >> 2) * CG + (kb) * GBK + (cb & 3) * 8),\
                (__attribute__((address_space(3))) unsigned int*)                \
                    (&ldsB[slot][0] + cb * 8),                                   \
                16, 0, 0);                                                       \
        }                                                                        \
    } while (0)

    GSTAGE(0, 0);

    for (int kb = 0; kb < GNKB; ++kb) {
        const int sl = kb & 1;
        if (kb + 1 < GNKB) {
            GSTAGE(sl ^ 1, kb + 1);   // writes slot read in iter kb-1 (done)
            asm volatile("s_waitcnt vmcnt(5)" ::: "memory");  // current ready
        } else {
            asm volatile("s_waitcnt vmcnt(0)" ::: "memory");
        }
        __builtin_amdgcn_s_barrier();
        __builtin_amdgcn_sched_barrier(0);

        bf16x8 af[8], bfr[4];
#pragma unroll
        for (int n = 0; n < 4; ++n)
            bfr[n] = *(const bf16x8*)&ldsB[sl][(wv * 64 + n * 16 + lr) * GBK + lk];
#pragma unroll
        for (int m = 0; m < 8; ++m)
            af[m] = *(const bf16x8*)&ldsA[sl][(m * 16 + lr) * GBK + lk];
#pragma unroll
        for (int m = 0; m < 8; ++m)
#pragma unroll
            for (int n = 0; n < 4; ++n)
                acc[m][n] = __builtin_amdgcn_mfma_f32_16x16x32_bf16(
                    af[m], bfr[n], acc[m][n], 0, 0, 0);

        __builtin_amdgcn_sched_barrier(0);
        __builtin_amdgcn_s_barrier();   // all reads of slot sl done
    }
#undef GSTAGE

    // epilogue: D frag layout col = lane&15, row = (lane>>4)*4 + r
    const int r0 = mt * 128 + ((l >> 4) << 2);
    const int cbase = wv * 64 + lr;    // within group's 512 cols
#pragma unroll
    for (int n = 0; n < 4; ++n) {
        int col = cbase + n * 16;
        float bv = bias[g * J_RANK + col];
#pragma unroll
        for (int m = 0; m < 8; ++m) {
            int row = r0 + m * 16;
            float* op = out + (size_t)row * C_IN + g * J_RANK + col;
#pragma unroll
            for (int r = 0; r < 4; ++r)
                op[(size_t)r * C_IN] = acc[m][n][r] + bv;
        }
    }
}

extern "C" void kernel_launch(void* const* d_in, const int* in_sizes, int n_in,
                              void* d_out, int out_size, void* d_ws, size_t ws_size,
                              hipStream_t stream) {
    const float* x    = (const float*)d_in[0];
    const int*   arr  = (const int*)d_in[1];
    const float* w    = (const float*)d_in[2];
    const float* bias = (const float*)d_in[3];
    float* out = (float*)d_out;

    // workspace: xp bf16 [8192][4096] (64MB) | wb bf16 [8][512][512] (4MB)
    unsigned short* xp = (unsigned short*)d_ws;
    unsigned short* wb = xp + (size_t)B_ROWS * C_IN;

    hipLaunchKernelGGL(convert_w_kernel, dim3((G_GRP * J_RANK * CG / 4 + 255) / 256),
                       dim3(256), 0, stream, w, wb, G_GRP * J_RANK * CG / 4);
    hipLaunchKernelGGL(permute_x_kernel, dim3(PERM_BLOCKS), dim3(256), 0, stream,
                       x, arr, xp);
    hipLaunchKernelGGL(gemm_kernel, dim3(G_GRP * 64), dim3(512), 0, stream,
                       xp, wb, bias, out);
}

// Round 7
// 110.107 us; speedup vs baseline: 1.1635x; 1.1635x over previous
//
#include <hip/hip_runtime.h>
#include <hip/hip_bf16.h>

#define B_ROWS 8192
#define C_IN   4096
#define G_GRP  8
#define CG     512
#define J_RANK 512

// ---- 8-phase GEMM geometry ----
#define BM 256
#define BN 256
#define BK 64
#define NKT (CG / BK)                 // 8 K-tiles

#define RPB    8                      // rows per permute block
#define PERM_BLOCKS (B_ROWS / RPB)    // 1024

typedef __attribute__((ext_vector_type(8))) short bf16x8;
typedef __attribute__((ext_vector_type(4))) float f32x4;
typedef __attribute__((ext_vector_type(8))) unsigned short u16x8;

struct ushort4v { unsigned short x, y, z, w; };

__device__ __forceinline__ unsigned short f2bf(float f) {
    unsigned int u = __float_as_uint(f);
    unsigned int r = (u + 0x7FFFu + ((u >> 16) & 1u)) >> 16;  // RNE
    return (unsigned short)r;
}

// ---------------- kernel 1: convert weights fp32 -> bf16 ----------------
__global__ __launch_bounds__(256) void convert_w_kernel(
    const float* __restrict__ w, unsigned short* __restrict__ wb, int n4) {
    int i = blockIdx.x * 256 + threadIdx.x;
    if (i >= n4) return;
    float4 v = ((const float4*)w)[i];
    ushort4v o;
    o.x = f2bf(v.x); o.y = f2bf(v.y); o.z = f2bf(v.z); o.w = f2bf(v.w);
    ((ushort4v*)wb)[i] = o;
}

// -------- kernel 2: gather-permute x, depth-3 LDS pipeline (R6, kept) ---
__global__ __launch_bounds__(256) void permute_x_kernel(
    const float* __restrict__ x, const int* __restrict__ arr,
    unsigned short* __restrict__ xp) {
    __shared__ float buf[3][C_IN];   // 48 KB
    const int tid  = threadIdx.x;
    const int row0 = blockIdx.x * RPB;

    // arrangements declared int64 in the reference; harness may hand int32.
    const bool is64 = (arr[1] == 0 && arr[3] == 0 && arr[5] == 0 && arr[7] == 0);

    int sidx[16];
#pragma unroll
    for (int pass = 0; pass < 2; ++pass)
#pragma unroll
        for (int k = 0; k < 8; ++k) {
            int p = pass * 2048 + tid * 8 + k;
            sidx[pass * 8 + k] = is64 ? arr[2 * p] : arr[p];
        }

#define PSTAGE(bufi, r)                                                      \
    do {                                                                     \
        const float* src_ = x + (size_t)(row0 + (r)) * C_IN;                 \
        _Pragma("unroll")                                                    \
        for (int i_ = 0; i_ < 4; ++i_) {                                     \
            int c_ = i_ * 256 + tid;                                         \
            __builtin_amdgcn_global_load_lds(                                \
                (const __attribute__((address_space(1))) unsigned int*)      \
                    (src_ + c_ * 4),                                         \
                (__attribute__((address_space(3))) unsigned int*)            \
                    (&buf[bufi][0] + c_ * 4),                                \
                16, 0, 0);                                                   \
        }                                                                    \
    } while (0)

    PSTAGE(0, 0);
    PSTAGE(1, 1);
    PSTAGE(2, 2);

#pragma unroll
    for (int r = 0; r < RPB; ++r) {
        if (r == 0)            asm volatile("s_waitcnt vmcnt(8)"  ::: "memory");
        else if (r == 1)       asm volatile("s_waitcnt vmcnt(10)" ::: "memory");
        else if (r == RPB - 2) asm volatile("s_waitcnt vmcnt(8)"  ::: "memory");
        else if (r == RPB - 1) asm volatile("s_waitcnt vmcnt(4)"  ::: "memory");
        else                   asm volatile("s_waitcnt vmcnt(12)" ::: "memory");
        __builtin_amdgcn_s_barrier();
        __builtin_amdgcn_sched_barrier(0);

        const int bi = r % 3;
        unsigned short* orow = xp + (size_t)(row0 + r) * C_IN;
#pragma unroll
        for (int pass = 0; pass < 2; ++pass) {
            u16x8 o;
#pragma unroll
            for (int k = 0; k < 8; ++k)
                o[k] = f2bf(buf[bi][sidx[pass * 8 + k]]);
            *(u16x8*)(orow + pass * 2048 + tid * 8) = o;
        }

        __builtin_amdgcn_sched_barrier(0);
        __builtin_amdgcn_s_barrier();
        if (r + 3 < RPB) PSTAGE(bi, r + 3);
    }
#undef PSTAGE
}

// ------------- kernel 3: grouped GEMM, 8-phase 256x256 (T2+T3+T4+T5) ----
// 512 blocks = 8 groups x 32 mt x 2 nt. 8 waves (2Mx4N), wave tile 128x64.
// BK=64, dbuf on K-tile parity, LDS 128KB (1 block/CU).
// Phases per K-tile: q=0..3, each {ds_read frags; stage 1 half-tile;
// [vmcnt]; barrier; lgkm0; setprio1; 16 MFMA; setprio0; barrier}.
// Stage slots: (kt,0):A0(kt+1) (kt,1):A1(kt+1) (kt,2):B0(kt+2) (kt,3):B1(kt+2)
// vmcnt(4) once per K-tile at phase 3 (covers K-tile kt+1's 4 halves).
// T2 swizzle: LDS[row][chunk] holds global chunk (chunk ^ (row&7));
// reads XOR with (lr&7) -> 64 lanes spread evenly over all 8 chunks/row.
__global__ __launch_bounds__(512, 2) void gemm_kernel(
    const unsigned short* __restrict__ Xp,   // [B][4096] bf16 (permuted)
    const unsigned short* __restrict__ Wb,   // [G][J][CG] bf16
    const float* __restrict__ bias,          // [G][J]
    float* __restrict__ out) {               // [B][4096] fp32
    __shared__ unsigned short ldsA[2][BM * BK];   // 2 x 32 KB
    __shared__ unsigned short ldsB[2][BN * BK];   // 2 x 32 KB

    const int tid = threadIdx.x;
    const int g   = blockIdx.x & 7;    // group -> XCD (512 % 8 == 0, bijective)
    const int idx = blockIdx.x >> 3;   // 0..63
    const int mt  = idx >> 1;          // 0..31
    const int nt  = idx & 1;

    const int l   = tid & 63;
    const int wv  = tid >> 6;          // 0..7
    const int wr  = wv >> 2;           // 0..1  (M half: rows wr*128..+127)
    const int wc  = wv & 3;            // 0..3  (N quarter: cols wc*64..+63)
    const int lr  = l & 15;
    const int lkq = l >> 4;            // 0..3
    const int rx  = lr & 7;            // read-side swizzle XOR

    const unsigned short* Ab = Xp + (size_t)(mt * BM) * C_IN + g * CG;
    const unsigned short* Bb = Wb + (size_t)g * J_RANK * CG + (size_t)(nt * BN) * CG;

    f32x4 acc[8][4];
#pragma unroll
    for (int m = 0; m < 8; ++m)
#pragma unroll
        for (int n = 0; n < 4; ++n) acc[m][n] = (f32x4){0.f, 0.f, 0.f, 0.f};

    // per-lane read bases (elements)
    const int aRow = (wr * 128 + lr) * BK;        // + m*16*BK
    const int bRow = (wc * 64 + lr) * BK;         // + n*16*BK
    int coff[2];
#pragma unroll
    for (int kk = 0; kk < 2; ++kk) coff[kk] = (((kk << 2) | lkq) ^ rx) * 8;

    // stage: half h of K-tile kt_ -> buf (kt_&1); 2 x 16B chunks per thread.
    // LDS dest linear (base + lane*16); global source pre-swizzled chunk.
#define STAGE_A(h, kt_)                                                       \
    do { const int p_ = (kt_) & 1;                                            \
        _Pragma("unroll")                                                     \
        for (int i_ = 0; i_ < 2; ++i_) {                                      \
            int c_ = i_ * 512 + tid;                                          \
            int rl_ = c_ >> 3, gc_ = (c_ & 7) ^ (rl_ & 7);                    \
            __builtin_amdgcn_global_load_lds(                                 \
                (const __attribute__((address_space(1))) unsigned int*)       \
                    (Ab + (size_t)((h) * 128 + rl_) * C_IN + (kt_) * BK + gc_ * 8), \
                (__attribute__((address_space(3))) unsigned int*)             \
                    (&ldsA[p_][0] + (h) * 8192 + c_ * 8),                     \
                16, 0, 0);                                                    \
        }                                                                     \
    } while (0)

#define STAGE_B(h, kt_)                                                       \
    do { const int p_ = (kt_) & 1;                                            \
        _Pragma("unroll")                                                     \
        for (int i_ = 0; i_ < 2; ++i_) {                                      \
            int c_ = i_ * 512 + tid;                                          \
            int rl_ = c_ >> 3, gc_ = (c_ & 7) ^ (rl_ & 7);                    \
            __builtin_amdgcn_global_load_lds(                                 \
                (const __attribute__((address_space(1))) unsigned int*)       \
                    (Bb + (size_t)((h) * 128 + rl_) * CG + (kt_) * BK + gc_ * 8), \
                (__attribute__((address_space(3))) unsigned int*)             \
                    (&ldsB[p_][0] + (h) * 8192 + c_ * 8),                     \
                16, 0, 0);                                                    \
        }                                                                     \
    } while (0)

#define LDA(m_, kk_) (*(const bf16x8*)&ldsA[buf][aRow + (m_) * 16 * BK + coff[kk_]])
#define LDB(n_, kk_) (*(const bf16x8*)&ldsB[buf][bRow + (n_) * 16 * BK + coff[kk_]])

#define MFMA_Q(q_)                                                            \
    _Pragma("unroll")                                                         \
    for (int mm_ = 0; mm_ < 2; ++mm_)                                         \
    _Pragma("unroll")                                                         \
    for (int n_ = 0; n_ < 4; ++n_)                                            \
    _Pragma("unroll")                                                         \
    for (int kk_ = 0; kk_ < 2; ++kk_)                                         \
        acc[2 * (q_) + mm_][n_] = __builtin_amdgcn_mfma_f32_16x16x32_bf16(    \
            af[mm_][kk_], bfr[n_][kk_], acc[2 * (q_) + mm_][n_], 0, 0, 0);

#define PHASE_TAIL()                                                          \
    __builtin_amdgcn_s_barrier();                                             \
    asm volatile("s_waitcnt lgkmcnt(0)" ::: "memory");                        \
    __builtin_amdgcn_sched_barrier(0);                                        \
    __builtin_amdgcn_s_setprio(1)

#define PHASE_END()                                                           \
    __builtin_amdgcn_s_setprio(0);                                            \
    __builtin_amdgcn_s_barrier()

    // ---- prologue: stage A(0), B(0), B(1); drain to A(0)+B(0) landed ----
    STAGE_A(0, 0); STAGE_A(1, 0);
    STAGE_B(0, 0); STAGE_B(1, 0);
    STAGE_B(0, 1); STAGE_B(1, 1);
    asm volatile("s_waitcnt vmcnt(4)" ::: "memory");   // A(0),B(0) landed
    __builtin_amdgcn_s_barrier();

    bf16x8 bfr[4][2], af[2][2];

    for (int kt = 0; kt < NKT; ++kt) {
        const int buf = kt & 1;

        // ---- phase 0: read B(all 8) + A(q0); stage A0(kt+1) ----
#pragma unroll
        for (int n = 0; n < 4; ++n)
#pragma unroll
            for (int kk = 0; kk < 2; ++kk) bfr[n][kk] = LDB(n, kk);
#pragma unroll
        for (int mm = 0; mm < 2; ++mm)
#pragma unroll
            for (int kk = 0; kk < 2; ++kk) af[mm][kk] = LDA(mm, kk);
        if (kt + 1 < NKT) STAGE_A(0, kt + 1);
        PHASE_TAIL();
        MFMA_Q(0);
        PHASE_END();

        // ---- phase 1: read A(q1); stage A1(kt+1) ----
#pragma unroll
        for (int mm = 0; mm < 2; ++mm)
#pragma unroll
            for (int kk = 0; kk < 2; ++kk) af[mm][kk] = LDA(2 + mm, kk);
        if (kt + 1 < NKT) STAGE_A(1, kt + 1);
        PHASE_TAIL();
        MFMA_Q(1);
        PHASE_END();

        // ---- phase 2: read A(q2); stage B0(kt+2) ----
#pragma unroll
        for (int mm = 0; mm < 2; ++mm)
#pragma unroll
            for (int kk = 0; kk < 2; ++kk) af[mm][kk] = LDA(4 + mm, kk);
        if (kt + 2 < NKT) STAGE_B(0, kt + 2);
        PHASE_TAIL();
        MFMA_Q(2);
        PHASE_END();

        // ---- phase 3: read A(q3); stage B1(kt+2); counted vmcnt ----
#pragma unroll
        for (int mm = 0; mm < 2; ++mm)
#pragma unroll
            for (int kk = 0; kk < 2; ++kk) af[mm][kk] = LDA(6 + mm, kk);
        if (kt + 2 < NKT) STAGE_B(1, kt + 2);
        if (kt <= NKT - 3)      asm volatile("s_waitcnt vmcnt(4)" ::: "memory");
        else if (kt == NKT - 2) asm volatile("s_waitcnt vmcnt(0)" ::: "memory");
        PHASE_TAIL();
        MFMA_Q(3);
        PHASE_END();
    }
#undef STAGE_A
#undef STAGE_B
#undef LDA
#undef LDB
#undef MFMA_Q
#undef PHASE_TAIL
#undef PHASE_END

    // epilogue: D frag layout col = lane&15, row = (lane>>4)*4 + r
    const int r0 = mt * BM + wr * 128 + (lkq << 2);
    const int cbase = nt * BN + wc * 64 + lr;   // within group's 512 cols
#pragma unroll
    for (int n = 0; n < 4; ++n) {
        int col = cbase + n * 16;
        float bv = bias[g * J_RANK + col];
#pragma unroll
        for (int m = 0; m < 8; ++m) {
            int row = r0 + m * 16;
            float* op = out + (size_t)row * C_IN + g * J_RANK + col;
#pragma unroll
            for (int r = 0; r < 4; ++r)
                op[(size_t)r * C_IN] = acc[m][n][r] + bv;
        }
    }
}

extern "C" void kernel_launch(void* const* d_in, const int* in_sizes, int n_in,
                              void* d_out, int out_size, void* d_ws, size_t ws_size,
                              hipStream_t stream) {
    const float* x    = (const float*)d_in[0];
    const int*   arr  = (const int*)d_in[1];
    const float* w    = (const float*)d_in[2];
    const float* bias = (const float*)d_in[3];
    float* out = (float*)d_out;

    // workspace: xp bf16 [8192][4096] (64MB) | wb bf16 [8][512][512] (4MB)
    unsigned short* xp = (unsigned short*)d_ws;
    unsigned short* wb = xp + (size_t)B_ROWS * C_IN;

    hipLaunchKernelGGL(convert_w_kernel, dim3((G_GRP * J_RANK * CG / 4 + 255) / 256),
                       dim3(256), 0, stream, w, wb, G_GRP * J_RANK * CG / 4);
    hipLaunchKernelGGL(permute_x_kernel, dim3(PERM_BLOCKS), dim3(256), 0, stream,
                       x, arr, xp);
    hipLaunchKernelGGL(gemm_kernel,
                       dim3(G_GRP * (B_ROWS / BM) * (J_RANK / BN)), dim3(512),
                       0, stream, xp, wb, bias, out);
}